// Round 1
// baseline (351.890 us; speedup 1.0000x reference)
//
#include <hip/hip_runtime.h>

// Problem constants
constexpr int CB = 2;     // batch
constexpr int CH = 128;   // H
constexpr int CW = 128;   // W
constexpr int CM = 8;     // heads
constexpr int CVv = 16;   // C_v = C/M

// ---------------------------------------------------------------------------
// Generic row-tiled GEMM: out[N,J] = A[N,KDIM] @ W[KDIM,J] + bias[J]
// blockDim.x == J; each block computes R rows. A rows staged in LDS
// (broadcast reads), each thread owns one output column -> W load reused
// across R rows in registers.
// ---------------------------------------------------------------------------
template<int KDIM, int J, int R>
__global__ __launch_bounds__(J) void gemm_bias_kernel(
    const float* __restrict__ A, const float* __restrict__ W,
    const float* __restrict__ bias, float* __restrict__ out, int N)
{
  const int j = threadIdx.x;
  const int row0 = blockIdx.x * R;
  __shared__ float As[R][KDIM];
  for (int idx = threadIdx.x; idx < R * KDIM; idx += J) {
    const int r = idx / KDIM, k = idx - r * KDIM;
    const int rr = row0 + r;
    As[r][k] = (rr < N) ? A[(size_t)rr * KDIM + k] : 0.f;
  }
  __syncthreads();

  float acc[R];
#pragma unroll
  for (int r = 0; r < R; ++r) acc[r] = 0.f;

#pragma unroll 4
  for (int k = 0; k < KDIM; ++k) {
    const float wv = W[k * J + j];
#pragma unroll
    for (int r = 0; r < R; ++r) acc[r] = fmaf(As[r][k], wv, acc[r]);
  }

  const float bv = bias[j];
#pragma unroll
  for (int r = 0; r < R; ++r) {
    const int rr = row0 + r;
    if (rr < N) out[(size_t)rr * J + j] = acc[r] + bv;
  }
}

// ---------------------------------------------------------------------------
// Fused softmax + scrambled bilinear sampling + attention-weighted reduce.
// One block per query q=(b,h,w), 128 threads: t = m*16 + c.
// Faithful index scramble (derived from the reference's permute+view):
//   k' = h>>5 ; x' = (w>>5) + (h&31)*4 ; y' = (c>>2) + (w&31)*4
//   l' = (c>>1)&1 ; cv' = s + 8*(c&1)   (s = softmax axis, 0..7)
//   p_q batch = (b*M+m) % B   (faithful torch .repeat quirk)
// ---------------------------------------------------------------------------
__global__ __launch_bounds__(128) void sample_attn_kernel(
    const float* __restrict__ Alog,    // [B*H*W, 64]
    const float* __restrict__ deltas,  // [B*H*W, 128]
    const float* __restrict__ p_q,     // [B, H, W, 2]
    const float* __restrict__ Wx0,     // [B, 64, 64, 128]
    const float* __restrict__ Wx1,     // [B, 128, 128, 128]
    float* __restrict__ P)             // [B*H*W, 128]
{
  const int q = blockIdx.x;
  const int w = q & (CW - 1);
  const int h = (q >> 7) & (CH - 1);
  const int b = q >> 14;
  const int t = threadIdx.x;
  const int m = t >> 4;
  const int c = t & 15;

  const int kk   = h >> 5;
  const int xp   = (w >> 5) + ((h & 31) << 2);
  const int yp   = (c >> 2) + ((w & 31) << 2);
  const int lp   = (c >> 1) & 1;
  const int half = c & 1;

  // --- softmax over the 8 (l,k) attention logits at the OUTPUT location ---
  const float* al = Alog + (size_t)q * 64 + m * 8;
  float lg[8];
  float mx = -3.0e38f;
#pragma unroll
  for (int s = 0; s < 8; ++s) { lg[s] = al[s]; mx = fmaxf(mx, lg[s]); }
  float se = 0.f;
#pragma unroll
  for (int s = 0; s < 8; ++s) { lg[s] = __expf(lg[s] - mx); se += lg[s]; }
  const float inv = 1.f / se;

  // --- sampling offset + reference point at the SCRAMBLED location ---
  const size_t qp = ((size_t)b * CH + yp) * CW + xp;
  const float dx = deltas[qp * 128 + m * 16 + lp * 8 + kk * 2 + 0];
  const float dy = deltas[qp * 128 + m * 16 + lp * 8 + kk * 2 + 1];

  const int pb = (b * CM + m) % CB;  // faithful quirk
  const size_t pqi = (((size_t)pb * CH + yp) * CW + xp) * 2;
  const float px = p_q[pqi + 0];
  const float py = p_q[pqi + 1];

  const int wl = lp ? 128 : 64;
  const int hl = wl;
  const float* img = lp ? Wx1 : Wx0;

  // grid_sample coords (align_corners=False, zeros padding), faithful math
  const float cx = px * (float)(wl - 1) + dx;
  const float cy = py * (float)(hl - 1) + dy;
  const float gx = 2.f * cx / (float)(wl - 1) - 1.f;
  const float gy = 2.f * cy / (float)(hl - 1) - 1.f;
  const float ix = ((gx + 1.f) * (float)wl - 1.f) * 0.5f;
  const float iy = ((gy + 1.f) * (float)hl - 1.f) * 0.5f;
  const float x0f = floorf(ix), y0f = floorf(iy);
  const float fx1 = ix - x0f, fy1 = iy - y0f;
  const float fx0 = 1.f - fx1, fy0 = 1.f - fy1;
  const int xi = (int)x0f, yi = (int)y0f;

  float acc[8];
#pragma unroll
  for (int s = 0; s < 8; ++s) acc[s] = 0.f;

  const int chanoff = m * 16 + half * 8;
#pragma unroll
  for (int dyc = 0; dyc < 2; ++dyc) {
    const int ys = yi + dyc;
    if (ys < 0 || ys >= hl) continue;
    const float wy = dyc ? fy1 : fy0;
#pragma unroll
    for (int dxc = 0; dxc < 2; ++dxc) {
      const int xs = xi + dxc;
      if (xs < 0 || xs >= wl) continue;
      const float wgt = wy * (dxc ? fx1 : fx0);
      const float* v = img + (((size_t)b * hl + ys) * wl + xs) * 128 + chanoff;
      const float4 v0 = *(const float4*)(v);
      const float4 v1 = *(const float4*)(v + 4);
      acc[0] = fmaf(wgt, v0.x, acc[0]);
      acc[1] = fmaf(wgt, v0.y, acc[1]);
      acc[2] = fmaf(wgt, v0.z, acc[2]);
      acc[3] = fmaf(wgt, v0.w, acc[3]);
      acc[4] = fmaf(wgt, v1.x, acc[4]);
      acc[5] = fmaf(wgt, v1.y, acc[5]);
      acc[6] = fmaf(wgt, v1.z, acc[6]);
      acc[7] = fmaf(wgt, v1.w, acc[7]);
    }
  }

  float o = 0.f;
#pragma unroll
  for (int s = 0; s < 8; ++s) o = fmaf(lg[s] * inv, acc[s], o);
  P[(size_t)q * 128 + t] = o;
}

// ---------------------------------------------------------------------------
extern "C" void kernel_launch(void* const* d_in, const int* in_sizes, int n_in,
                              void* d_out, int out_size, void* d_ws, size_t ws_size,
                              hipStream_t stream)
{
  const float* z_q = (const float*)d_in[0];
  const float* x0  = (const float*)d_in[1];
  const float* x1  = (const float*)d_in[2];
  const float* p_q = (const float*)d_in[3];
  const float* Wq  = (const float*)d_in[4];
  const float* bq  = (const float*)d_in[5];
  const float* Wd  = (const float*)d_in[6];
  const float* bd  = (const float*)d_in[7];
  const float* Wa  = (const float*)d_in[8];
  const float* ba  = (const float*)d_in[9];
  const float* Wp  = (const float*)d_in[10];
  const float* bp  = (const float*)d_in[11];
  const float* Wm  = (const float*)d_in[12];
  const float* bm  = (const float*)d_in[13];

  float* ws = (float*)d_ws;
  const int NQ = CB * CH * CW;   // 32768
  const int N0 = CB * 64 * 64;   // 8192

  float* zq   = ws;               // 4194304 floats (reused as P afterwards)
  float* dl   = ws + 4194304;     // deltas  [NQ,128]
  float* Alog = ws + 8388608;     // [NQ,64]
  float* Wx0  = ws + 10485760;    // [N0,128]
  float* Wx1  = ws + 11534336;    // [NQ,128]

  constexpr int R = 16;
  gemm_bias_kernel<128,128,R><<<NQ / R, 128, 0, stream>>>(z_q, Wq, bq, zq, NQ);
  gemm_bias_kernel<128,128,R><<<NQ / R, 128, 0, stream>>>(zq, Wd, bd, dl, NQ);
  gemm_bias_kernel<128, 64,R><<<NQ / R,  64, 0, stream>>>(zq, Wa, ba, Alog, NQ);
  gemm_bias_kernel<128,128,R><<<N0 / R, 128, 0, stream>>>(x0, Wp, bp, Wx0, N0);
  gemm_bias_kernel<128,128,R><<<NQ / R, 128, 0, stream>>>(x1, Wp, bp, Wx1, NQ);

  float* P = zq;  // zq dead after deltas/Alog
  sample_attn_kernel<<<NQ, 128, 0, stream>>>(Alog, dl, p_q, Wx0, Wx1, P);

  gemm_bias_kernel<128,128,R><<<NQ / R, 128, 0, stream>>>(P, Wm, bm, (float*)d_out, NQ);
}

// Round 2
// 299.078 us; speedup vs baseline: 1.1766x; 1.1766x over previous
//
#include <hip/hip_runtime.h>

// Problem constants
constexpr int CB = 2;     // batch
constexpr int CH = 128;   // H
constexpr int CW = 128;   // W
constexpr int CM = 8;     // heads

// ---------------------------------------------------------------------------
// Register-tiled GEMM: out[N,J] = A[N,128] @ W[128,J] + bias[J]
// 256 threads/block. Tile = ROWS x J, per-thread 4 rows x 4 cols.
// A staged in LDS (ds_read_b128 over k, broadcast across col-groups);
// W read from global as float4 (L2-resident, coalesced, reused by all blocks).
// Per 4-k chunk: 64 FMA vs 4 ds_read_b128 + 4 global float4 -> VALU-bound.
// Requires N % ROWS == 0 (true for all uses here).
// ---------------------------------------------------------------------------
template<int KDIM, int J>
__global__ __launch_bounds__(256) void gemm_bias_kernel(
    const float* __restrict__ A, const float* __restrict__ W,
    const float* __restrict__ bias, float* __restrict__ out)
{
  constexpr int JG   = J / 4;        // column groups of 4
  constexpr int RG   = 256 / JG;     // row groups of 4
  constexpr int ROWS = RG * 4;

  const int t  = threadIdx.x;
  const int jg = t % JG;
  const int rg = t / JG;
  const int row0 = blockIdx.x * ROWS;

  __shared__ float As[ROWS][KDIM];

  // cooperative linear copy of the A tile (rows are contiguous)
  {
    const float4* Ag  = (const float4*)(A + (size_t)row0 * KDIM);
    float4*       Asv = (float4*)&As[0][0];
    constexpr int NV = ROWS * KDIM / 4;
#pragma unroll
    for (int i = t; i < NV; i += 256) Asv[i] = Ag[i];
  }
  __syncthreads();

  float acc[4][4];
#pragma unroll
  for (int r = 0; r < 4; ++r)
#pragma unroll
    for (int c = 0; c < 4; ++c) acc[r][c] = 0.f;

  const int r0 = rg * 4;
  const float* Wp = W + jg * 4;

#pragma unroll 2
  for (int k0 = 0; k0 < KDIM; k0 += 4) {
    float4 wv[4];
#pragma unroll
    for (int kk = 0; kk < 4; ++kk)
      wv[kk] = *(const float4*)(Wp + (size_t)(k0 + kk) * J);
    float4 av[4];
#pragma unroll
    for (int r = 0; r < 4; ++r)
      av[r] = *(const float4*)&As[r0 + r][k0];

#pragma unroll
    for (int r = 0; r < 4; ++r) {
      const float a0 = av[r].x, a1 = av[r].y, a2 = av[r].z, a3 = av[r].w;
      acc[r][0] = fmaf(a0, wv[0].x, acc[r][0]);
      acc[r][1] = fmaf(a0, wv[0].y, acc[r][1]);
      acc[r][2] = fmaf(a0, wv[0].z, acc[r][2]);
      acc[r][3] = fmaf(a0, wv[0].w, acc[r][3]);
      acc[r][0] = fmaf(a1, wv[1].x, acc[r][0]);
      acc[r][1] = fmaf(a1, wv[1].y, acc[r][1]);
      acc[r][2] = fmaf(a1, wv[1].z, acc[r][2]);
      acc[r][3] = fmaf(a1, wv[1].w, acc[r][3]);
      acc[r][0] = fmaf(a2, wv[2].x, acc[r][0]);
      acc[r][1] = fmaf(a2, wv[2].y, acc[r][1]);
      acc[r][2] = fmaf(a2, wv[2].z, acc[r][2]);
      acc[r][3] = fmaf(a2, wv[2].w, acc[r][3]);
      acc[r][0] = fmaf(a3, wv[3].x, acc[r][0]);
      acc[r][1] = fmaf(a3, wv[3].y, acc[r][1]);
      acc[r][2] = fmaf(a3, wv[3].z, acc[r][2]);
      acc[r][3] = fmaf(a3, wv[3].w, acc[r][3]);
    }
  }

  const float4 bv = *(const float4*)(bias + jg * 4);
#pragma unroll
  for (int r = 0; r < 4; ++r) {
    float4 o;
    o.x = acc[r][0] + bv.x;
    o.y = acc[r][1] + bv.y;
    o.z = acc[r][2] + bv.z;
    o.w = acc[r][3] + bv.w;
    *(float4*)(out + (size_t)(row0 + r0 + r) * J + jg * 4) = o;
  }
}

// ---------------------------------------------------------------------------
// Fused softmax + scrambled bilinear sampling + attention-weighted reduce.
// One block per query q=(b,h,w), 128 threads: t = m*16 + c.
// Faithful index scramble (derived from the reference's permute+view):
//   k' = h>>5 ; x' = (w>>5) + (h&31)*4 ; y' = (c>>2) + (w&31)*4
//   l' = (c>>1)&1 ; cv' = s + 8*(c&1)   (s = softmax axis, 0..7)
//   p_q batch = (b*M+m) % B   (faithful torch .repeat quirk)
// ---------------------------------------------------------------------------
__global__ __launch_bounds__(128) void sample_attn_kernel(
    const float* __restrict__ Alog,    // [B*H*W, 64]
    const float* __restrict__ deltas,  // [B*H*W, 128]
    const float* __restrict__ p_q,     // [B, H, W, 2]
    const float* __restrict__ Wx0,     // [B, 64, 64, 128]
    const float* __restrict__ Wx1,     // [B, 128, 128, 128]
    float* __restrict__ P)             // [B*H*W, 128]
{
  const int q = blockIdx.x;
  const int w = q & (CW - 1);
  const int h = (q >> 7) & (CH - 1);
  const int b = q >> 14;
  const int t = threadIdx.x;
  const int m = t >> 4;
  const int c = t & 15;

  const int kk   = h >> 5;
  const int xp   = (w >> 5) + ((h & 31) << 2);
  const int yp   = (c >> 2) + ((w & 31) << 2);
  const int lp   = (c >> 1) & 1;
  const int half = c & 1;

  // --- softmax over the 8 (l,k) attention logits at the OUTPUT location ---
  const float* al = Alog + (size_t)q * 64 + m * 8;
  float lg[8];
  float mx = -3.0e38f;
#pragma unroll
  for (int s = 0; s < 8; ++s) { lg[s] = al[s]; mx = fmaxf(mx, lg[s]); }
  float se = 0.f;
#pragma unroll
  for (int s = 0; s < 8; ++s) { lg[s] = __expf(lg[s] - mx); se += lg[s]; }
  const float inv = 1.f / se;

  // --- sampling offset + reference point at the SCRAMBLED location ---
  const size_t qp = ((size_t)b * CH + yp) * CW + xp;
  const float dx = deltas[qp * 128 + m * 16 + lp * 8 + kk * 2 + 0];
  const float dy = deltas[qp * 128 + m * 16 + lp * 8 + kk * 2 + 1];

  const int pb = (b * CM + m) % CB;  // faithful quirk
  const size_t pqi = (((size_t)pb * CH + yp) * CW + xp) * 2;
  const float px = p_q[pqi + 0];
  const float py = p_q[pqi + 1];

  const int wl = lp ? 128 : 64;
  const int hl = wl;
  const float* img = lp ? Wx1 : Wx0;

  // grid_sample coords (align_corners=False, zeros padding), faithful math
  const float cx = px * (float)(wl - 1) + dx;
  const float cy = py * (float)(hl - 1) + dy;
  const float gx = 2.f * cx / (float)(wl - 1) - 1.f;
  const float gy = 2.f * cy / (float)(hl - 1) - 1.f;
  const float ix = ((gx + 1.f) * (float)wl - 1.f) * 0.5f;
  const float iy = ((gy + 1.f) * (float)hl - 1.f) * 0.5f;
  const float x0f = floorf(ix), y0f = floorf(iy);
  const float fx1 = ix - x0f, fy1 = iy - y0f;
  const float fx0 = 1.f - fx1, fy0 = 1.f - fy1;
  const int xi = (int)x0f, yi = (int)y0f;

  float acc[8];
#pragma unroll
  for (int s = 0; s < 8; ++s) acc[s] = 0.f;

  const int chanoff = m * 16 + half * 8;
#pragma unroll
  for (int dyc = 0; dyc < 2; ++dyc) {
    const int ys = yi + dyc;
    if (ys < 0 || ys >= hl) continue;
    const float wy = dyc ? fy1 : fy0;
#pragma unroll
    for (int dxc = 0; dxc < 2; ++dxc) {
      const int xs = xi + dxc;
      if (xs < 0 || xs >= wl) continue;
      const float wgt = wy * (dxc ? fx1 : fx0);
      const float* v = img + (((size_t)b * hl + ys) * wl + xs) * 128 + chanoff;
      const float4 v0 = *(const float4*)(v);
      const float4 v1 = *(const float4*)(v + 4);
      acc[0] = fmaf(wgt, v0.x, acc[0]);
      acc[1] = fmaf(wgt, v0.y, acc[1]);
      acc[2] = fmaf(wgt, v0.z, acc[2]);
      acc[3] = fmaf(wgt, v0.w, acc[3]);
      acc[4] = fmaf(wgt, v1.x, acc[4]);
      acc[5] = fmaf(wgt, v1.y, acc[5]);
      acc[6] = fmaf(wgt, v1.z, acc[6]);
      acc[7] = fmaf(wgt, v1.w, acc[7]);
    }
  }

  float o = 0.f;
#pragma unroll
  for (int s = 0; s < 8; ++s) o = fmaf(lg[s] * inv, acc[s], o);
  P[(size_t)q * 128 + t] = o;
}

// ---------------------------------------------------------------------------
extern "C" void kernel_launch(void* const* d_in, const int* in_sizes, int n_in,
                              void* d_out, int out_size, void* d_ws, size_t ws_size,
                              hipStream_t stream)
{
  const float* z_q = (const float*)d_in[0];
  const float* x0  = (const float*)d_in[1];
  const float* x1  = (const float*)d_in[2];
  const float* p_q = (const float*)d_in[3];
  const float* Wq  = (const float*)d_in[4];
  const float* bq  = (const float*)d_in[5];
  const float* Wd  = (const float*)d_in[6];
  const float* bd  = (const float*)d_in[7];
  const float* Wa  = (const float*)d_in[8];
  const float* ba  = (const float*)d_in[9];
  const float* Wp  = (const float*)d_in[10];
  const float* bp  = (const float*)d_in[11];
  const float* Wm  = (const float*)d_in[12];
  const float* bm  = (const float*)d_in[13];

  float* ws = (float*)d_ws;
  const int NQ = CB * CH * CW;   // 32768
  const int N0 = CB * 64 * 64;   // 8192

  float* zq   = ws;               // 4194304 floats (reused as P afterwards)
  float* dl   = ws + 4194304;     // deltas  [NQ,128]
  float* Alog = ws + 8388608;     // [NQ,64]
  float* Wx0  = ws + 10485760;    // [N0,128]
  float* Wx1  = ws + 11534336;    // [NQ,128]

  // J=128 -> tile 32 rows; J=64 -> tile 64 rows
  gemm_bias_kernel<128,128><<<NQ / 32, 256, 0, stream>>>(z_q, Wq, bq, zq);
  gemm_bias_kernel<128,128><<<NQ / 32, 256, 0, stream>>>(zq, Wd, bd, dl);
  gemm_bias_kernel<128, 64><<<NQ / 64, 256, 0, stream>>>(zq, Wa, ba, Alog);
  gemm_bias_kernel<128,128><<<N0 / 32, 256, 0, stream>>>(x0, Wp, bp, Wx0);
  gemm_bias_kernel<128,128><<<NQ / 32, 256, 0, stream>>>(x1, Wp, bp, Wx1);

  float* P = zq;  // zq dead after deltas/Alog
  sample_attn_kernel<<<NQ, 128, 0, stream>>>(Alog, dl, p_q, Wx0, Wx1, P);

  gemm_bias_kernel<128,128><<<NQ / 32, 256, 0, stream>>>(P, Wm, bm, (float*)d_out);
}

// Round 3
// 288.827 us; speedup vs baseline: 1.2183x; 1.0355x over previous
//
#include <hip/hip_runtime.h>
#include <hip/hip_bf16.h>

// Problem constants
constexpr int CB = 2;     // batch
constexpr int CH = 128;   // H
constexpr int CW = 128;   // W
constexpr int CM = 8;     // heads

typedef __bf16 bf16x8 __attribute__((ext_vector_type(8)));
typedef float  f32x4  __attribute__((ext_vector_type(4)));

__device__ __forceinline__ unsigned short f2bf(float f) {
  __hip_bfloat16 h = __float2bfloat16(f);
  return *reinterpret_cast<unsigned short*>(&h);
}
__device__ __forceinline__ float bf2f(unsigned short u) {
  __hip_bfloat16 h;
  *reinterpret_cast<unsigned short*>(&h) = u;
  return __bfloat162float(h);
}

// ---------------------------------------------------------------------------
// Weight prep: transpose + split-bf16 all 5 weight matrices.
// Slot m (32768 ushorts): hi[J][128] at base, lo[J][128] at base+16384.
// ---------------------------------------------------------------------------
__global__ __launch_bounds__(256) void prep_weights_kernel(
    const float* __restrict__ W0, const float* __restrict__ W1,
    const float* __restrict__ W2, const float* __restrict__ W3,
    const float* __restrict__ W4, unsigned short* __restrict__ out)
{
  const float* Ws[5] = {W0, W1, W2, W3, W4};
  const int    Js[5] = {128, 128, 64, 128, 128};
  const int m = blockIdx.y;
  const float* W = Ws[m];
  const int J = Js[m];
  unsigned short* o = out + m * 32768;
  for (int idx = blockIdx.x * 256 + threadIdx.x; idx < 128 * J;
       idx += gridDim.x * 256) {
    const int k = idx / J, j = idx - k * J;   // W[k][j]
    const float f = W[idx];
    const unsigned short hi = f2bf(f);
    const unsigned short lo = f2bf(f - bf2f(hi));
    o[j * 128 + k]         = hi;
    o[16384 + j * 128 + k] = lo;
  }
}

// ---------------------------------------------------------------------------
// Split-bf16 MFMA GEMM: out[N,J] = A[N,128] @ W[128,J] + bias[J], fp32-quality.
// 256 threads = 4 waves; block tile 64 rows x J cols; wave tile 16 rows x J.
// A staged fp32->bf16 hi/lo in LDS with XOR swizzle (both sides, rule #21).
// B fragments read from pre-transposed k-contiguous Wt (L2-resident).
// mfma_f32_16x16x32_bf16; 3 MFMAs per (jt,k0): hh + lh + hl (lo*lo dropped).
// Fragment maps: A lane l -> row l&15, k (l>>4)*8+i (contiguous);
//                B lane l -> col l&15, k (l>>4)*8+i;
//                D lane l -> col l&15, row (l>>4)*4+reg  [m89-verified].
// ---------------------------------------------------------------------------
template<int J>
__global__ __launch_bounds__(256) void gemm_mfma_split(
    const float* __restrict__ A,
    const unsigned short* __restrict__ Wt,   // hi [J][128]; lo at +16384
    const float* __restrict__ bias,
    float* __restrict__ out)
{
  constexpr int JT = J / 16;
  __shared__ unsigned short Ahi[64 * 128];
  __shared__ unsigned short Alo[64 * 128];

  const int t = threadIdx.x;
  const int row0 = blockIdx.x * 64;

  // ---- stage + split A tile (64 rows x 128 k) ----
  {
    const float4* Ag = (const float4*)(A + (size_t)row0 * 128);
#pragma unroll
    for (int i = 0; i < 8; ++i) {
      const int v = t + i * 256;        // float4 index within tile
      const float4 f = Ag[v];
      const int flat = v * 4;
      const int r = flat >> 7;
      const int k = flat & 127;
      const int byte = (r * 256 + k * 2) ^ ((r & 7) << 4);
      const float ff[4] = {f.x, f.y, f.z, f.w};
      ushort4 h, lo;
      unsigned short* hp = (unsigned short*)&h;
      unsigned short* lp = (unsigned short*)&lo;
#pragma unroll
      for (int u = 0; u < 4; ++u) {
        hp[u] = f2bf(ff[u]);
        lp[u] = f2bf(ff[u] - bf2f(hp[u]));
      }
      *(ushort4*)((char*)Ahi + byte) = h;
      *(ushort4*)((char*)Alo + byte) = lo;
    }
  }
  __syncthreads();

  const int w  = t >> 6;       // wave 0..3
  const int l  = t & 63;
  const int lr = l & 15;       // row (A) / col (B,D)
  const int kg = l >> 4;       // k-group 0..3

  f32x4 acc[JT];
#pragma unroll
  for (int jt = 0; jt < JT; ++jt) acc[jt] = (f32x4){0.f, 0.f, 0.f, 0.f};

  const int r = w * 16 + lr;
  const unsigned short* Wlo = Wt + 16384;

#pragma unroll
  for (int k0 = 0; k0 < 128; k0 += 32) {
    const int abyte = (r * 256 + (k0 + kg * 8) * 2) ^ ((r & 7) << 4);
    const bf16x8 ah = *(const bf16x8*)((const char*)Ahi + abyte);
    const bf16x8 al = *(const bf16x8*)((const char*)Alo + abyte);
#pragma unroll
    for (int jt = 0; jt < JT; ++jt) {
      const int boff = (jt * 16 + lr) * 128 + k0 + kg * 8;
      const bf16x8 bh = *(const bf16x8*)(Wt + boff);
      const bf16x8 bl = *(const bf16x8*)(Wlo + boff);
      acc[jt] = __builtin_amdgcn_mfma_f32_16x16x32_bf16(ah, bh, acc[jt], 0, 0, 0);
      acc[jt] = __builtin_amdgcn_mfma_f32_16x16x32_bf16(al, bh, acc[jt], 0, 0, 0);
      acc[jt] = __builtin_amdgcn_mfma_f32_16x16x32_bf16(ah, bl, acc[jt], 0, 0, 0);
    }
  }

  // ---- epilogue: bias + store fp32 ----
#pragma unroll
  for (int jt = 0; jt < JT; ++jt) {
    const float bv = bias[jt * 16 + lr];
#pragma unroll
    for (int rg = 0; rg < 4; ++rg) {
      const int orow = row0 + w * 16 + kg * 4 + rg;
      out[(size_t)orow * J + jt * 16 + lr] = acc[jt][rg] + bv;
    }
  }
}

// ---------------------------------------------------------------------------
// Fused softmax + scrambled bilinear sampling + attention-weighted reduce.
// One block per query q=(b,h,w), 128 threads: t = m*16 + c.
// Faithful index scramble (derived from the reference's permute+view):
//   k' = h>>5 ; x' = (w>>5) + (h&31)*4 ; y' = (c>>2) + (w&31)*4
//   l' = (c>>1)&1 ; cv' = s + 8*(c&1)   (s = softmax axis, 0..7)
//   p_q batch = (b*M+m) % B   (faithful torch .repeat quirk)
// ---------------------------------------------------------------------------
__global__ __launch_bounds__(128) void sample_attn_kernel(
    const float* __restrict__ Alog,    // [B*H*W, 64]
    const float* __restrict__ deltas,  // [B*H*W, 128]
    const float* __restrict__ p_q,     // [B, H, W, 2]
    const float* __restrict__ Wx0,     // [B, 64, 64, 128]
    const float* __restrict__ Wx1,     // [B, 128, 128, 128]
    float* __restrict__ P)             // [B*H*W, 128]
{
  const int q = blockIdx.x;
  const int w = q & (CW - 1);
  const int h = (q >> 7) & (CH - 1);
  const int b = q >> 14;
  const int t = threadIdx.x;
  const int m = t >> 4;
  const int c = t & 15;

  const int kk   = h >> 5;
  const int xp   = (w >> 5) + ((h & 31) << 2);
  const int yp   = (c >> 2) + ((w & 31) << 2);
  const int lp   = (c >> 1) & 1;
  const int half = c & 1;

  const float* al = Alog + (size_t)q * 64 + m * 8;
  float lg[8];
  float mx = -3.0e38f;
#pragma unroll
  for (int s = 0; s < 8; ++s) { lg[s] = al[s]; mx = fmaxf(mx, lg[s]); }
  float se = 0.f;
#pragma unroll
  for (int s = 0; s < 8; ++s) { lg[s] = __expf(lg[s] - mx); se += lg[s]; }
  const float inv = 1.f / se;

  const size_t qp = ((size_t)b * CH + yp) * CW + xp;
  const float dx = deltas[qp * 128 + m * 16 + lp * 8 + kk * 2 + 0];
  const float dy = deltas[qp * 128 + m * 16 + lp * 8 + kk * 2 + 1];

  const int pb = (b * CM + m) % CB;  // faithful quirk
  const size_t pqi = (((size_t)pb * CH + yp) * CW + xp) * 2;
  const float px = p_q[pqi + 0];
  const float py = p_q[pqi + 1];

  const int wl = lp ? 128 : 64;
  const int hl = wl;
  const float* img = lp ? Wx1 : Wx0;

  const float cx = px * (float)(wl - 1) + dx;
  const float cy = py * (float)(hl - 1) + dy;
  const float gx = 2.f * cx / (float)(wl - 1) - 1.f;
  const float gy = 2.f * cy / (float)(hl - 1) - 1.f;
  const float ix = ((gx + 1.f) * (float)wl - 1.f) * 0.5f;
  const float iy = ((gy + 1.f) * (float)hl - 1.f) * 0.5f;
  const float x0f = floorf(ix), y0f = floorf(iy);
  const float fx1 = ix - x0f, fy1 = iy - y0f;
  const float fx0 = 1.f - fx1, fy0 = 1.f - fy1;
  const int xi = (int)x0f, yi = (int)y0f;

  float acc[8];
#pragma unroll
  for (int s = 0; s < 8; ++s) acc[s] = 0.f;

  const int chanoff = m * 16 + half * 8;
#pragma unroll
  for (int dyc = 0; dyc < 2; ++dyc) {
    const int ys = yi + dyc;
    if (ys < 0 || ys >= hl) continue;
    const float wy = dyc ? fy1 : fy0;
#pragma unroll
    for (int dxc = 0; dxc < 2; ++dxc) {
      const int xs = xi + dxc;
      if (xs < 0 || xs >= wl) continue;
      const float wgt = wy * (dxc ? fx1 : fx0);
      const float* v = img + (((size_t)b * hl + ys) * wl + xs) * 128 + chanoff;
      const float4 v0 = *(const float4*)(v);
      const float4 v1 = *(const float4*)(v + 4);
      acc[0] = fmaf(wgt, v0.x, acc[0]);
      acc[1] = fmaf(wgt, v0.y, acc[1]);
      acc[2] = fmaf(wgt, v0.z, acc[2]);
      acc[3] = fmaf(wgt, v0.w, acc[3]);
      acc[4] = fmaf(wgt, v1.x, acc[4]);
      acc[5] = fmaf(wgt, v1.y, acc[5]);
      acc[6] = fmaf(wgt, v1.z, acc[6]);
      acc[7] = fmaf(wgt, v1.w, acc[7]);
    }
  }

  float o = 0.f;
#pragma unroll
  for (int s = 0; s < 8; ++s) o = fmaf(lg[s] * inv, acc[s], o);
  P[(size_t)q * 128 + t] = o;
}

// ---------------------------------------------------------------------------
extern "C" void kernel_launch(void* const* d_in, const int* in_sizes, int n_in,
                              void* d_out, int out_size, void* d_ws, size_t ws_size,
                              hipStream_t stream)
{
  const float* z_q = (const float*)d_in[0];
  const float* x0  = (const float*)d_in[1];
  const float* x1  = (const float*)d_in[2];
  const float* p_q = (const float*)d_in[3];
  const float* Wq  = (const float*)d_in[4];
  const float* bq  = (const float*)d_in[5];
  const float* Wd  = (const float*)d_in[6];
  const float* bd  = (const float*)d_in[7];
  const float* Wa  = (const float*)d_in[8];
  const float* ba  = (const float*)d_in[9];
  const float* Wp  = (const float*)d_in[10];
  const float* bp  = (const float*)d_in[11];
  const float* Wm  = (const float*)d_in[12];
  const float* bm  = (const float*)d_in[13];

  float* ws = (float*)d_ws;
  const int NQ = CB * CH * CW;   // 32768
  const int N0 = CB * 64 * 64;   // 8192

  // weight area: 5 slots x 32768 ushorts = 81920 floats
  unsigned short* Wts = (unsigned short*)ws;
  unsigned short* WtQ = Wts;                // slot 0: Wq
  unsigned short* WtD = Wts + 1 * 32768;    // slot 1: Wd
  unsigned short* WtA = Wts + 2 * 32768;    // slot 2: Wa (J=64)
  unsigned short* WtP = Wts + 3 * 32768;    // slot 3: Wp
  unsigned short* WtM = Wts + 4 * 32768;    // slot 4: Wm

  float* zq   = ws + 81920;      // [NQ,128] (reused as P)
  float* dl   = zq + 4194304;    // deltas [NQ,128]
  float* Alog = dl + 4194304;    // [NQ,64]
  float* Wx0  = Alog + 2097152;  // [N0,128]
  float* Wx1  = Wx0 + 1048576;   // [NQ,128]

  prep_weights_kernel<<<dim3(64, 5), 256, 0, stream>>>(Wq, Wd, Wa, Wp, Wm, Wts);

  gemm_mfma_split<128><<<NQ / 64, 256, 0, stream>>>(z_q, WtQ, bq, zq);
  gemm_mfma_split<128><<<NQ / 64, 256, 0, stream>>>(zq,  WtD, bd, dl);
  gemm_mfma_split< 64><<<NQ / 64, 256, 0, stream>>>(zq,  WtA, ba, Alog);
  gemm_mfma_split<128><<<N0 / 64, 256, 0, stream>>>(x0,  WtP, bp, Wx0);
  gemm_mfma_split<128><<<NQ / 64, 256, 0, stream>>>(x1,  WtP, bp, Wx1);

  float* P = zq;  // zq dead after deltas/Alog
  sample_attn_kernel<<<NQ, 128, 0, stream>>>(Alog, dl, p_q, Wx0, Wx1, P);

  gemm_mfma_split<128><<<NQ / 64, 256, 0, stream>>>(P, WtM, bm, (float*)d_out);
}

// Round 4
// 236.143 us; speedup vs baseline: 1.4902x; 1.2231x over previous
//
#include <hip/hip_runtime.h>
#include <hip/hip_bf16.h>

// Problem constants
constexpr int CB = 2;     // batch
constexpr int CH = 128;   // H
constexpr int CW = 128;   // W
constexpr int CM = 8;     // heads

typedef __bf16 bf16x8 __attribute__((ext_vector_type(8)));
typedef float  f32x4  __attribute__((ext_vector_type(4)));
typedef unsigned short us8 __attribute__((ext_vector_type(8)));

__device__ __forceinline__ unsigned short f2bf(float f) {
  __hip_bfloat16 h = __float2bfloat16(f);
  return *reinterpret_cast<unsigned short*>(&h);
}
__device__ __forceinline__ float bf2f(unsigned short u) {
  __hip_bfloat16 h;
  *reinterpret_cast<unsigned short*>(&h) = u;
  return __bfloat162float(h);
}

// ---------------------------------------------------------------------------
// Prep: (a) compose WC = Wq @ [Wd | Wa]  -> bf16-hi, transposed [j][k]
//       (b) transpose+round Wp, Wm       -> bf16-hi, [j][k]
//       (c) composed bias bda[j] = bq @ [Wd|Wa] + [bd|ba]   (fp32)
// ---------------------------------------------------------------------------
__global__ __launch_bounds__(256) void prep_all_kernel(
    const float* __restrict__ Wq, const float* __restrict__ bq,
    const float* __restrict__ Wd, const float* __restrict__ bd,
    const float* __restrict__ Wa, const float* __restrict__ ba,
    const float* __restrict__ Wp, const float* __restrict__ Wm,
    unsigned short* __restrict__ WtDA, unsigned short* __restrict__ WtP,
    unsigned short* __restrict__ WtM, float* __restrict__ bda)
{
  const int blk = blockIdx.x, t = threadIdx.x;
  if (blk < 96) {                        // compose: 192*128 = 24576 elems
    const int idx = blk * 256 + t;
    const int j = idx >> 7, k = idx & 127;
    float s = 0.f;
    if (j < 128) {
      for (int i = 0; i < 128; ++i) s = fmaf(Wq[k * 128 + i], Wd[i * 128 + j], s);
    } else {
      for (int i = 0; i < 128; ++i) s = fmaf(Wq[k * 128 + i], Wa[i * 64 + (j - 128)], s);
    }
    WtDA[j * 128 + k] = f2bf(s);
  } else if (blk < 224) {                // transpose-round Wp, Wm
    const int idx = (blk - 96) * 256 + t;   // 0..32767
    if (idx < 16384) {
      const int k = idx >> 7, j = idx & 127;
      WtP[j * 128 + k] = f2bf(Wp[idx]);
    } else {
      const int i2 = idx - 16384;
      const int k = i2 >> 7, j = i2 & 127;
      WtM[j * 128 + k] = f2bf(Wm[i2]);
    }
  } else {                               // composed bias (192)
    if (t < 192) {
      const int j = t;
      float s = (j < 128) ? bd[j] : ba[j - 128];
      if (j < 128) {
        for (int i = 0; i < 128; ++i) s = fmaf(bq[i], Wd[i * 128 + j], s);
      } else {
        for (int i = 0; i < 128; ++i) s = fmaf(bq[i], Wa[i * 64 + (j - 128)], s);
      }
      bda[j] = s;
    }
  }
}

// ---------------------------------------------------------------------------
// Split-bf16 MFMA GEMM body: out[64 rows, J] = A[64,128] @ W + bias.
// No LDS, no barriers: A fragments (k-contiguous per lane) loaded straight
// from global fp32 and split to bf16 hi/lo in registers; B hi fragments from
// pre-transposed k-contiguous Wt (L2-resident). 2 MFMAs per (jt,k0): hh + lh.
// Fragment maps (m89-verified): A lane l -> row l&15, k (l>>4)*8+i;
// B lane l -> col l&15, k (l>>4)*8+i; D lane l -> col l&15, row (l>>4)*4+reg.
// ---------------------------------------------------------------------------
template<int J, bool ZPART>
__device__ __forceinline__ void gemm_body(
    const float* __restrict__ Arow0,              // A + row0_local*128
    const unsigned short* __restrict__ Wt,        // hi [J][128]
    const float* __restrict__ bias,
    float* __restrict__ out0,                     // ZPART: dl ; else out
    float* __restrict__ out1,                     // ZPART: Alog
    int row0g)                                    // global output row base
{
  constexpr int JT = J / 16;
  const int t  = threadIdx.x;
  const int w  = t >> 6;
  const int l  = t & 63;
  const int lr = l & 15;
  const int kg = l >> 4;

  f32x4 acc[JT];
#pragma unroll
  for (int jt = 0; jt < JT; ++jt) acc[jt] = (f32x4){0.f, 0.f, 0.f, 0.f};

  const float* Ap = Arow0 + (w * 16 + lr) * 128 + kg * 8;

#pragma unroll
  for (int k0 = 0; k0 < 128; k0 += 32) {
    const float4 f0 = *(const float4*)(Ap + k0);
    const float4 f1 = *(const float4*)(Ap + k0 + 4);
    const float ff[8] = {f0.x, f0.y, f0.z, f0.w, f1.x, f1.y, f1.z, f1.w};
    us8 uh, ul;
#pragma unroll
    for (int i = 0; i < 8; ++i) {
      const unsigned short hi = f2bf(ff[i]);
      uh[i] = hi;
      ul[i] = f2bf(ff[i] - bf2f(hi));
    }
    const bf16x8 ah = __builtin_bit_cast(bf16x8, uh);
    const bf16x8 al = __builtin_bit_cast(bf16x8, ul);

    const unsigned short* Wk = Wt + lr * 128 + k0 + kg * 8;
#pragma unroll
    for (int jt = 0; jt < JT; ++jt) {
      const bf16x8 bh = *(const bf16x8*)(Wk + jt * 16 * 128);
      acc[jt] = __builtin_amdgcn_mfma_f32_16x16x32_bf16(ah, bh, acc[jt], 0, 0, 0);
      acc[jt] = __builtin_amdgcn_mfma_f32_16x16x32_bf16(al, bh, acc[jt], 0, 0, 0);
    }
  }

#pragma unroll
  for (int jt = 0; jt < JT; ++jt) {
    const int col = jt * 16 + lr;
    const float bv = bias[col];
#pragma unroll
    for (int rg = 0; rg < 4; ++rg) {
      const int row = row0g + w * 16 + kg * 4 + rg;
      const float v = acc[jt][rg] + bv;
      if (ZPART) {
        if (jt < 8) out0[(size_t)row * 128 + col] = v;
        else        out1[(size_t)row * 64 + (col - 128)] = v;
      } else {
        out0[(size_t)row * J + col] = v;
      }
    }
  }
}

// Fused pre-sample GEMM: blocks [0,nZ) -> z_q @ WtDA -> (deltas | Alog);
// blocks [nZ, nZ+640) -> {x0,x1} @ WtP -> WxAll.
__global__ __launch_bounds__(256) void pre_gemm_kernel(
    const float* __restrict__ z_q, const float* __restrict__ x0,
    const float* __restrict__ x1,
    const unsigned short* __restrict__ WtDA, const float* __restrict__ bda,
    const unsigned short* __restrict__ WtP,  const float* __restrict__ bp,
    float* __restrict__ dl, float* __restrict__ Alog,
    float* __restrict__ WxAll, int nZ)
{
  const int blk = blockIdx.x;
  if (blk < nZ) {
    const int r0 = blk * 64;
    gemm_body<192, true>(z_q + (size_t)r0 * 128, WtDA, bda, dl, Alog, r0);
  } else {
    const int r0 = (blk - nZ) * 64;
    const float* A = (r0 < 8192) ? (x0 + (size_t)r0 * 128)
                                 : (x1 + (size_t)(r0 - 8192) * 128);
    gemm_body<128, false>(A, WtP, bp, WxAll, nullptr, r0);
  }
}

__global__ __launch_bounds__(256) void final_gemm_kernel(
    const float* __restrict__ P, const unsigned short* __restrict__ WtM,
    const float* __restrict__ bm, float* __restrict__ out)
{
  const int r0 = blockIdx.x * 64;
  gemm_body<128, false>(P + (size_t)r0 * 128, WtM, bm, out, nullptr, r0);
}

// ---------------------------------------------------------------------------
// Fused softmax + scrambled bilinear sampling + attention-weighted reduce.
// One block per query q=(b,h,w), 128 threads: t = m*16 + c.
// Scramble: k' = h>>5 ; x' = (w>>5)+(h&31)*4 ; y' = (c>>2)+(w&31)*4
//           l' = (c>>1)&1 ; cv' = s + 8*(c&1) ; p_q batch = (b*M+m)%B
// Branchless gathers: clamped addresses, validity-zeroed weights, all 8
// dwordx4 loads issued in one clause before the softmax math.
// ---------------------------------------------------------------------------
__global__ __launch_bounds__(128) void sample_attn_kernel(
    const float* __restrict__ Alog,    // [B*H*W, 64]
    const float* __restrict__ deltas,  // [B*H*W, 128]
    const float* __restrict__ p_q,     // [B, H, W, 2]
    const float* __restrict__ Wx0,     // [B, 64, 64, 128]
    const float* __restrict__ Wx1,     // [B, 128, 128, 128]
    float* __restrict__ P)             // [B*H*W, 128]
{
  const int q = blockIdx.x;
  const int w = q & (CW - 1);
  const int h = (q >> 7) & (CH - 1);
  const int b = q >> 14;
  const int t = threadIdx.x;
  const int m = t >> 4;
  const int c = t & 15;

  const int kk   = h >> 5;
  const int xp   = (w >> 5) + ((h & 31) << 2);
  const int yp   = (c >> 2) + ((w & 31) << 2);
  const int lp   = (c >> 1) & 1;
  const int half = c & 1;

  // --- sampling offset + reference point at the SCRAMBLED location ---
  const size_t qp = ((size_t)b * CH + yp) * CW + xp;
  const float2 dxy = *(const float2*)(deltas + qp * 128 + m * 16 + lp * 8 + kk * 2);

  const int pb = (b * CM + m) % CB;  // faithful quirk
  const float2 pq2 = *(const float2*)(p_q + ((((size_t)pb * CH + yp) * CW + xp) * 2));

  const int wl = lp ? 128 : 64;
  const int hl = wl;
  const float* img = lp ? Wx1 : Wx0;

  // grid_sample coords (align_corners=False, zeros padding), faithful math
  const float cx = pq2.x * (float)(wl - 1) + dxy.x;
  const float cy = pq2.y * (float)(hl - 1) + dxy.y;
  const float gx = 2.f * cx / (float)(wl - 1) - 1.f;
  const float gy = 2.f * cy / (float)(hl - 1) - 1.f;
  const float ix = ((gx + 1.f) * (float)wl - 1.f) * 0.5f;
  const float iy = ((gy + 1.f) * (float)hl - 1.f) * 0.5f;
  const float x0f = floorf(ix), y0f = floorf(iy);
  const float fx1 = ix - x0f, fy1 = iy - y0f;
  const float fx0 = 1.f - fx1, fy0 = 1.f - fy1;
  const int xi = (int)x0f, yi = (int)y0f;

  // clamped addresses + validity
  const float vx0 = ((unsigned)xi < (unsigned)wl) ? 1.f : 0.f;
  const float vx1 = ((unsigned)(xi + 1) < (unsigned)wl) ? 1.f : 0.f;
  const float vy0 = ((unsigned)yi < (unsigned)hl) ? 1.f : 0.f;
  const float vy1 = ((unsigned)(yi + 1) < (unsigned)hl) ? 1.f : 0.f;
  const int xc0 = min(max(xi, 0), wl - 1);
  const int xc1 = min(max(xi + 1, 0), wl - 1);
  const int yc0 = min(max(yi, 0), hl - 1);
  const int yc1 = min(max(yi + 1, 0), hl - 1);

  const float* base = img + (size_t)b * hl * wl * 128 + (m * 16 + half * 8);
  const float* p00 = base + (size_t)(yc0 * wl + xc0) * 128;
  const float* p01 = base + (size_t)(yc0 * wl + xc1) * 128;
  const float* p10 = base + (size_t)(yc1 * wl + xc0) * 128;
  const float* p11 = base + (size_t)(yc1 * wl + xc1) * 128;

  // 8 independent gathers, single clause
  const float4 a00 = ((const float4*)p00)[0], b00 = ((const float4*)p00)[1];
  const float4 a01 = ((const float4*)p01)[0], b01 = ((const float4*)p01)[1];
  const float4 a10 = ((const float4*)p10)[0], b10 = ((const float4*)p10)[1];
  const float4 a11 = ((const float4*)p11)[0], b11 = ((const float4*)p11)[1];

  // --- softmax over the 8 (l,k) logits at the OUTPUT location (overlaps
  //     with the gather latency above) ---
  const float* al = Alog + (size_t)q * 64 + m * 8;
  const float4 al0 = ((const float4*)al)[0];
  const float4 al1 = ((const float4*)al)[1];
  float lg[8] = {al0.x, al0.y, al0.z, al0.w, al1.x, al1.y, al1.z, al1.w};
  float mx = -3.0e38f;
#pragma unroll
  for (int s = 0; s < 8; ++s) mx = fmaxf(mx, lg[s]);
  float se = 0.f;
#pragma unroll
  for (int s = 0; s < 8; ++s) { lg[s] = __expf(lg[s] - mx); se += lg[s]; }
  const float inv = 1.f / se;

  const float w00 = fy0 * fx0 * vy0 * vx0;
  const float w01 = fy0 * fx1 * vy0 * vx1;
  const float w10 = fy1 * fx0 * vy1 * vx0;
  const float w11 = fy1 * fx1 * vy1 * vx1;

  float acc[8];
  acc[0] = w00 * a00.x; acc[1] = w00 * a00.y; acc[2] = w00 * a00.z; acc[3] = w00 * a00.w;
  acc[4] = w00 * b00.x; acc[5] = w00 * b00.y; acc[6] = w00 * b00.z; acc[7] = w00 * b00.w;
  acc[0] = fmaf(w01, a01.x, acc[0]); acc[1] = fmaf(w01, a01.y, acc[1]);
  acc[2] = fmaf(w01, a01.z, acc[2]); acc[3] = fmaf(w01, a01.w, acc[3]);
  acc[4] = fmaf(w01, b01.x, acc[4]); acc[5] = fmaf(w01, b01.y, acc[5]);
  acc[6] = fmaf(w01, b01.z, acc[6]); acc[7] = fmaf(w01, b01.w, acc[7]);
  acc[0] = fmaf(w10, a10.x, acc[0]); acc[1] = fmaf(w10, a10.y, acc[1]);
  acc[2] = fmaf(w10, a10.z, acc[2]); acc[3] = fmaf(w10, a10.w, acc[3]);
  acc[4] = fmaf(w10, b10.x, acc[4]); acc[5] = fmaf(w10, b10.y, acc[5]);
  acc[6] = fmaf(w10, b10.z, acc[6]); acc[7] = fmaf(w10, b10.w, acc[7]);
  acc[0] = fmaf(w11, a11.x, acc[0]); acc[1] = fmaf(w11, a11.y, acc[1]);
  acc[2] = fmaf(w11, a11.z, acc[2]); acc[3] = fmaf(w11, a11.w, acc[3]);
  acc[4] = fmaf(w11, b11.x, acc[4]); acc[5] = fmaf(w11, b11.y, acc[5]);
  acc[6] = fmaf(w11, b11.z, acc[6]); acc[7] = fmaf(w11, b11.w, acc[7]);

  float o = 0.f;
#pragma unroll
  for (int s = 0; s < 8; ++s) o = fmaf(lg[s] * inv, acc[s], o);
  P[(size_t)q * 128 + t] = o;
}

// ---------------------------------------------------------------------------
extern "C" void kernel_launch(void* const* d_in, const int* in_sizes, int n_in,
                              void* d_out, int out_size, void* d_ws, size_t ws_size,
                              hipStream_t stream)
{
  const float* z_q = (const float*)d_in[0];
  const float* x0  = (const float*)d_in[1];
  const float* x1  = (const float*)d_in[2];
  const float* p_q = (const float*)d_in[3];
  const float* Wq  = (const float*)d_in[4];
  const float* bq  = (const float*)d_in[5];
  const float* Wd  = (const float*)d_in[6];
  const float* bd  = (const float*)d_in[7];
  const float* Wa  = (const float*)d_in[8];
  const float* ba  = (const float*)d_in[9];
  const float* Wp  = (const float*)d_in[10];
  const float* bp  = (const float*)d_in[11];
  const float* Wm  = (const float*)d_in[12];
  const float* bm  = (const float*)d_in[13];

  float* ws = (float*)d_ws;
  const int NQ = CB * CH * CW;   // 32768

  // bf16 weight area
  unsigned short* Wts  = (unsigned short*)ws;
  unsigned short* WtDA = Wts;               // [192][128] hi (24576)
  unsigned short* WtP  = Wts + 24576;       // [128][128] hi (16384)
  unsigned short* WtM  = Wts + 40960;       // [128][128] hi (16384)
  float* bda   = ws + 28672;                // 192 composed bias

  float* dl    = ws + 28864;                // deltas [NQ,128]
  float* Alog  = dl + 4194304;              // [NQ,64]
  float* WxAll = Alog + 2097152;            // [40960,128]: Wx0 then Wx1
  float* P     = WxAll + 5242880;           // [NQ,128]

  float* Wx0 = WxAll;
  float* Wx1 = WxAll + (size_t)8192 * 128;

  prep_all_kernel<<<225, 256, 0, stream>>>(Wq, bq, Wd, bd, Wa, ba, Wp, Wm,
                                           WtDA, WtP, WtM, bda);

  const int nZ = NQ / 64;                   // 512 z-part blocks
  pre_gemm_kernel<<<nZ + 640, 256, 0, stream>>>(z_q, x0, x1, WtDA, bda,
                                                WtP, bp, dl, Alog, WxAll, nZ);

  sample_attn_kernel<<<NQ, 128, 0, stream>>>(Alog, dl, p_q, Wx0, Wx1, P);

  final_gemm_kernel<<<NQ / 64, 256, 0, stream>>>(P, WtM, bm, (float*)d_out);
}

// Round 5
// 200.025 us; speedup vs baseline: 1.7592x; 1.1806x over previous
//
#include <hip/hip_runtime.h>
#include <hip/hip_bf16.h>

// Problem constants
constexpr int CB = 2;     // batch
constexpr int CH = 128;   // H
constexpr int CW = 128;   // W
constexpr int CM = 8;     // heads

typedef __bf16 bf16x8 __attribute__((ext_vector_type(8)));
typedef float  f32x4  __attribute__((ext_vector_type(4)));
typedef unsigned short us8 __attribute__((ext_vector_type(8)));

__device__ __forceinline__ unsigned short f2bf(float f) {
  __hip_bfloat16 h = __float2bfloat16(f);
  return *reinterpret_cast<unsigned short*>(&h);
}
__device__ __forceinline__ float bf2f(unsigned short u) {
  __hip_bfloat16 h;
  *reinterpret_cast<unsigned short*>(&h) = u;
  return __bfloat162float(h);
}

// ---------------------------------------------------------------------------
// Prep: (a) compose WC = Wq @ [Wd | Wa]  -> bf16-hi, transposed [j][k]
//       (b) transpose+round Wp, Wm       -> bf16-hi, [j][k]
//       (c) composed bias bda[j] = bq @ [Wd|Wa] + [bd|ba]   (fp32)
// ---------------------------------------------------------------------------
__global__ __launch_bounds__(256) void prep_all_kernel(
    const float* __restrict__ Wq, const float* __restrict__ bq,
    const float* __restrict__ Wd, const float* __restrict__ bd,
    const float* __restrict__ Wa, const float* __restrict__ ba,
    const float* __restrict__ Wp, const float* __restrict__ Wm,
    unsigned short* __restrict__ WtDA, unsigned short* __restrict__ WtP,
    unsigned short* __restrict__ WtM, float* __restrict__ bda)
{
  const int blk = blockIdx.x, t = threadIdx.x;
  if (blk < 96) {                        // compose: 192*128 = 24576 elems
    const int idx = blk * 256 + t;
    const int j = idx >> 7, k = idx & 127;
    float s = 0.f;
    if (j < 128) {
      for (int i = 0; i < 128; ++i) s = fmaf(Wq[k * 128 + i], Wd[i * 128 + j], s);
    } else {
      for (int i = 0; i < 128; ++i) s = fmaf(Wq[k * 128 + i], Wa[i * 64 + (j - 128)], s);
    }
    WtDA[j * 128 + k] = f2bf(s);
  } else if (blk < 224) {                // transpose-round Wp, Wm
    const int idx = (blk - 96) * 256 + t;   // 0..32767
    if (idx < 16384) {
      const int k = idx >> 7, j = idx & 127;
      WtP[j * 128 + k] = f2bf(Wp[idx]);
    } else {
      const int i2 = idx - 16384;
      const int k = i2 >> 7, j = i2 & 127;
      WtM[j * 128 + k] = f2bf(Wm[i2]);
    }
  } else {                               // composed bias (192)
    if (t < 192) {
      const int j = t;
      float s = (j < 128) ? bd[j] : ba[j - 128];
      if (j < 128) {
        for (int i = 0; i < 128; ++i) s = fmaf(bq[i], Wd[i * 128 + j], s);
      } else {
        for (int i = 0; i < 128; ++i) s = fmaf(bq[i], Wa[i * 64 + (j - 128)], s);
      }
      bda[j] = s;
    }
  }
}

// ---------------------------------------------------------------------------
// Fused pre-sample GEMM (one dispatch):
//  blocks [0,nZ):    z_q @ WtDA (J=192, bf16-hi only) -> dl2 (scrambled) + Alog
//  blocks [nZ,+640): {x0,x1} @ WtP (J=128, split hi+lo A) -> Wx (bf16)
// Fragment maps (m89-verified): A lane l -> row l&15, k (l>>4)*8+i;
// B lane l -> col l&15, k (l>>4)*8+i; D lane l -> col l&15, row (l>>4)*4+reg.
// dl2 layout: [row][kk][m][lp][2] so each (row,kk) slice is read by exactly
// one sample block, contiguous (kills the 256 MB dl re-fetch).
// ---------------------------------------------------------------------------
__global__ __launch_bounds__(256) void pre_gemm_kernel(
    const float* __restrict__ z_q, const float* __restrict__ x0,
    const float* __restrict__ x1,
    const unsigned short* __restrict__ WtDA, const float* __restrict__ bda,
    const unsigned short* __restrict__ WtP,  const float* __restrict__ bp,
    float* __restrict__ dl2, float* __restrict__ Alog,
    unsigned short* __restrict__ Wx, int nZ)
{
  const int t  = threadIdx.x;
  const int w  = t >> 6;
  const int l  = t & 63;
  const int lr = l & 15;
  const int kg = l >> 4;
  const int blk = blockIdx.x;

  if (blk < nZ) {
    // ---------------- z-part: J=192, bf16-hi A only ----------------
    const int r0 = blk * 64;
    const float* Ap = z_q + (size_t)(r0 + w * 16 + lr) * 128 + kg * 8;

    f32x4 acc[12];
#pragma unroll
    for (int jt = 0; jt < 12; ++jt) acc[jt] = (f32x4){0.f, 0.f, 0.f, 0.f};

#pragma unroll
    for (int k0 = 0; k0 < 128; k0 += 32) {
      const float4 f0 = *(const float4*)(Ap + k0);
      const float4 f1 = *(const float4*)(Ap + k0 + 4);
      const float ff[8] = {f0.x, f0.y, f0.z, f0.w, f1.x, f1.y, f1.z, f1.w};
      us8 uh;
#pragma unroll
      for (int i = 0; i < 8; ++i) uh[i] = f2bf(ff[i]);
      const bf16x8 ah = __builtin_bit_cast(bf16x8, uh);

      const unsigned short* Wk = WtDA + lr * 128 + k0 + kg * 8;
#pragma unroll
      for (int jt = 0; jt < 12; ++jt) {
        const bf16x8 bh = *(const bf16x8*)(Wk + jt * 16 * 128);
        acc[jt] = __builtin_amdgcn_mfma_f32_16x16x32_bf16(ah, bh, acc[jt], 0, 0, 0);
      }
    }

    // scrambled column offset within dl2 row: [kk][m][lp][i]
    const int scol = ((lr >> 1) & 3) * 32 + ((lr >> 3) & 1) * 2 + (lr & 1);
#pragma unroll
    for (int jt = 0; jt < 8; ++jt) {
      const float bv = bda[jt * 16 + lr];
#pragma unroll
      for (int rg = 0; rg < 4; ++rg) {
        const int row = r0 + w * 16 + kg * 4 + rg;
        dl2[(size_t)row * 128 + jt * 4 + scol] = acc[jt][rg] + bv;
      }
    }
#pragma unroll
    for (int jt = 8; jt < 12; ++jt) {
      const int col = (jt - 8) * 16 + lr;
      const float bv = bda[128 + col];
#pragma unroll
      for (int rg = 0; rg < 4; ++rg) {
        const int row = r0 + w * 16 + kg * 4 + rg;
        Alog[(size_t)row * 64 + col] = acc[jt][rg] + bv;
      }
    }
  } else {
    // ---------------- x-part: J=128, split hi+lo A, bf16 out ----------------
    const int r0 = (blk - nZ) * 64;
    const float* A = (r0 < 8192) ? (x0 + (size_t)r0 * 128)
                                 : (x1 + (size_t)(r0 - 8192) * 128);
    const float* Ap = A + (size_t)(w * 16 + lr) * 128 + kg * 8;

    f32x4 acc[8];
#pragma unroll
    for (int jt = 0; jt < 8; ++jt) acc[jt] = (f32x4){0.f, 0.f, 0.f, 0.f};

#pragma unroll
    for (int k0 = 0; k0 < 128; k0 += 32) {
      const float4 f0 = *(const float4*)(Ap + k0);
      const float4 f1 = *(const float4*)(Ap + k0 + 4);
      const float ff[8] = {f0.x, f0.y, f0.z, f0.w, f1.x, f1.y, f1.z, f1.w};
      us8 uh, ul;
#pragma unroll
      for (int i = 0; i < 8; ++i) {
        const unsigned short hi = f2bf(ff[i]);
        uh[i] = hi;
        ul[i] = f2bf(ff[i] - bf2f(hi));
      }
      const bf16x8 ah = __builtin_bit_cast(bf16x8, uh);
      const bf16x8 al = __builtin_bit_cast(bf16x8, ul);

      const unsigned short* Wk = WtP + lr * 128 + k0 + kg * 8;
#pragma unroll
      for (int jt = 0; jt < 8; ++jt) {
        const bf16x8 bh = *(const bf16x8*)(Wk + jt * 16 * 128);
        acc[jt] = __builtin_amdgcn_mfma_f32_16x16x32_bf16(ah, bh, acc[jt], 0, 0, 0);
        acc[jt] = __builtin_amdgcn_mfma_f32_16x16x32_bf16(al, bh, acc[jt], 0, 0, 0);
      }
    }

#pragma unroll
    for (int jt = 0; jt < 8; ++jt) {
      const int col = jt * 16 + lr;
      const float bv = bp[col];
#pragma unroll
      for (int rg = 0; rg < 4; ++rg) {
        const int row = r0 + w * 16 + kg * 4 + rg;
        Wx[(size_t)row * 128 + col] = f2bf(acc[jt][rg] + bv);
      }
    }
  }
}

// ---------------------------------------------------------------------------
// Final GEMM: out[NQ,128] = Pbf(bf16) @ WtM(bf16-hi) + bm.  A fragments are
// direct ushort8 loads (no conversion); 1 MFMA per (jt,k0).
// ---------------------------------------------------------------------------
__global__ __launch_bounds__(256) void final_gemm_kernel(
    const unsigned short* __restrict__ Pbf,
    const unsigned short* __restrict__ WtM,
    const float* __restrict__ bm, float* __restrict__ out)
{
  const int t  = threadIdx.x;
  const int w  = t >> 6;
  const int l  = t & 63;
  const int lr = l & 15;
  const int kg = l >> 4;
  const int r0 = blockIdx.x * 64;

  const unsigned short* Ap = Pbf + (size_t)(r0 + w * 16 + lr) * 128 + kg * 8;

  f32x4 acc[8];
#pragma unroll
  for (int jt = 0; jt < 8; ++jt) acc[jt] = (f32x4){0.f, 0.f, 0.f, 0.f};

#pragma unroll
  for (int k0 = 0; k0 < 128; k0 += 32) {
    const bf16x8 av = *(const bf16x8*)(Ap + k0);
    const unsigned short* Wk = WtM + lr * 128 + k0 + kg * 8;
#pragma unroll
    for (int jt = 0; jt < 8; ++jt) {
      const bf16x8 bh = *(const bf16x8*)(Wk + jt * 16 * 128);
      acc[jt] = __builtin_amdgcn_mfma_f32_16x16x32_bf16(av, bh, acc[jt], 0, 0, 0);
    }
  }

#pragma unroll
  for (int jt = 0; jt < 8; ++jt) {
    const int col = jt * 16 + lr;
    const float bv = bm[col];
#pragma unroll
    for (int rg = 0; rg < 4; ++rg) {
      const int row = r0 + w * 16 + kg * 4 + rg;
      out[(size_t)row * 128 + col] = acc[jt][rg] + bv;
    }
  }
}

// ---------------------------------------------------------------------------
// Fused softmax + scrambled bilinear sampling + attention-weighted reduce.
// One block per query q=(b,h,w), 128 threads: t = m*16 + c.
// Scramble: k' = h>>5 ; x' = (w>>5)+(h&31)*4 ; y' = (c>>2)+(w&31)*4
//           l' = (c>>1)&1 ; cv' = s + 8*(c&1) ; p_q batch = (b*M+m)%B
// dl2 is pre-scrambled [row][kk][m][lp][2] -> one contiguous 128B slice per
// (row,kk), each read by exactly one block. Wx is bf16. Output P is bf16.
// ---------------------------------------------------------------------------
__global__ __launch_bounds__(128) void sample_attn_kernel(
    const float* __restrict__ Alog,          // [B*H*W, 64]
    const float* __restrict__ dl2,           // [B*H*W][kk][m][lp][2]
    const float* __restrict__ p_q,           // [B, H, W, 2]
    const unsigned short* __restrict__ Wx,   // rows 0..8191 = x0, 8192.. = x1
    unsigned short* __restrict__ Pbf)        // [B*H*W, 128] bf16
{
  const int q = blockIdx.x;
  const int w = q & (CW - 1);
  const int h = (q >> 7) & (CH - 1);
  const int b = q >> 14;
  const int t = threadIdx.x;
  const int m = t >> 4;
  const int c = t & 15;

  const int kk   = h >> 5;
  const int xp   = (w >> 5) + ((h & 31) << 2);
  const int yp   = (c >> 2) + ((w & 31) << 2);
  const int lp   = (c >> 1) & 1;
  const int half = c & 1;

  // --- independent loads first: delta, ref point, logits ---
  const size_t qp = ((size_t)b * CH + yp) * CW + xp;
  const float2 dxy = *(const float2*)(dl2 + qp * 128 + kk * 32 + m * 4 + lp * 2);

  const int pb = (b * CM + m) % CB;  // faithful quirk
  const float2 pq2 = *(const float2*)(p_q + ((((size_t)pb * CH + yp) * CW + xp) * 2));

  const float* al = Alog + (size_t)q * 64 + m * 8;
  const float4 al0 = ((const float4*)al)[0];
  const float4 al1 = ((const float4*)al)[1];

  const int wl = lp ? 128 : 64;
  const int hl = wl;
  const int imgbase = lp ? (8192 + b * 16384) : (b * 4096);

  // grid_sample coords (align_corners=False, zeros padding), faithful math
  const float cx = pq2.x * (float)(wl - 1) + dxy.x;
  const float cy = pq2.y * (float)(hl - 1) + dxy.y;
  const float gx = 2.f * cx / (float)(wl - 1) - 1.f;
  const float gy = 2.f * cy / (float)(hl - 1) - 1.f;
  const float ix = ((gx + 1.f) * (float)wl - 1.f) * 0.5f;
  const float iy = ((gy + 1.f) * (float)hl - 1.f) * 0.5f;
  const float x0f = floorf(ix), y0f = floorf(iy);
  const float fx1 = ix - x0f, fy1 = iy - y0f;
  const float fx0 = 1.f - fx1, fy0 = 1.f - fy1;
  const int xi = (int)x0f, yi = (int)y0f;

  // clamped addresses + validity
  const float vx0 = ((unsigned)xi < (unsigned)wl) ? 1.f : 0.f;
  const float vx1 = ((unsigned)(xi + 1) < (unsigned)wl) ? 1.f : 0.f;
  const float vy0 = ((unsigned)yi < (unsigned)hl) ? 1.f : 0.f;
  const float vy1 = ((unsigned)(yi + 1) < (unsigned)hl) ? 1.f : 0.f;
  const int xc0 = min(max(xi, 0), wl - 1);
  const int xc1 = min(max(xi + 1, 0), wl - 1);
  const int yc0 = min(max(yi, 0), hl - 1);
  const int yc1 = min(max(yi + 1, 0), hl - 1);

  const unsigned short* base = Wx + (size_t)imgbase * 128 + (m * 16 + half * 8);
  const unsigned short* p00 = base + (size_t)(yc0 * wl + xc0) * 128;
  const unsigned short* p01 = base + (size_t)(yc0 * wl + xc1) * 128;
  const unsigned short* p10 = base + (size_t)(yc1 * wl + xc0) * 128;
  const unsigned short* p11 = base + (size_t)(yc1 * wl + xc1) * 128;

  // 4 independent 16B gathers, single clause
  const us8 g00 = *(const us8*)p00;
  const us8 g01 = *(const us8*)p01;
  const us8 g10 = *(const us8*)p10;
  const us8 g11 = *(const us8*)p11;

  // --- softmax (overlaps gather latency) ---
  float lg[8] = {al0.x, al0.y, al0.z, al0.w, al1.x, al1.y, al1.z, al1.w};
  float mx = -3.0e38f;
#pragma unroll
  for (int s = 0; s < 8; ++s) mx = fmaxf(mx, lg[s]);
  float se = 0.f;
#pragma unroll
  for (int s = 0; s < 8; ++s) { lg[s] = __expf(lg[s] - mx); se += lg[s]; }
  const float inv = 1.f / se;

  const float w00 = fy0 * fx0 * vy0 * vx0;
  const float w01 = fy0 * fx1 * vy0 * vx1;
  const float w10 = fy1 * fx0 * vy1 * vx0;
  const float w11 = fy1 * fx1 * vy1 * vx1;

  float acc[8];
#pragma unroll
  for (int s = 0; s < 8; ++s) {
    float v = w00 * bf2f(g00[s]);
    v = fmaf(w01, bf2f(g01[s]), v);
    v = fmaf(w10, bf2f(g10[s]), v);
    v = fmaf(w11, bf2f(g11[s]), v);
    acc[s] = v;
  }

  float o = 0.f;
#pragma unroll
  for (int s = 0; s < 8; ++s) o = fmaf(lg[s] * inv, acc[s], o);
  Pbf[(size_t)q * 128 + t] = f2bf(o);
}

// ---------------------------------------------------------------------------
extern "C" void kernel_launch(void* const* d_in, const int* in_sizes, int n_in,
                              void* d_out, int out_size, void* d_ws, size_t ws_size,
                              hipStream_t stream)
{
  const float* z_q = (const float*)d_in[0];
  const float* x0  = (const float*)d_in[1];
  const float* x1  = (const float*)d_in[2];
  const float* p_q = (const float*)d_in[3];
  const float* Wq  = (const float*)d_in[4];
  const float* bq  = (const float*)d_in[5];
  const float* Wd  = (const float*)d_in[6];
  const float* bd  = (const float*)d_in[7];
  const float* Wa  = (const float*)d_in[8];
  const float* ba  = (const float*)d_in[9];
  const float* Wp  = (const float*)d_in[10];
  const float* bp  = (const float*)d_in[11];
  const float* Wm  = (const float*)d_in[12];
  const float* bm  = (const float*)d_in[13];

  float* ws = (float*)d_ws;
  const int NQ = CB * CH * CW;   // 32768

  // bf16 weight area (ushorts): WtDA 24576 | WtP 16384 | WtM 16384
  unsigned short* Wts  = (unsigned short*)ws;
  unsigned short* WtDA = Wts;
  unsigned short* WtP  = Wts + 24576;
  unsigned short* WtM  = Wts + 40960;
  float* bda = ws + 28672;                        // 192 composed bias

  float* dl2  = ws + 28864;                       // [NQ,128] fp32 scrambled
  float* Alog = dl2 + 4194304;                    // [NQ,64] fp32
  unsigned short* Wx  = (unsigned short*)(Alog + 2097152);   // [40960,128] bf16
  unsigned short* Pbf = Wx + 5242880;             // [NQ,128] bf16

  prep_all_kernel<<<225, 256, 0, stream>>>(Wq, bq, Wd, bd, Wa, ba, Wp, Wm,
                                           WtDA, WtP, WtM, bda);

  const int nZ = NQ / 64;                         // 512 z-part blocks
  pre_gemm_kernel<<<nZ + 640, 256, 0, stream>>>(z_q, x0, x1, WtDA, bda,
                                                WtP, bp, dl2, Alog, Wx, nZ);

  sample_attn_kernel<<<NQ, 128, 0, stream>>>(Alog, dl2, p_q, Wx, Pbf);

  final_gemm_kernel<<<NQ / 64, 256, 0, stream>>>(Pbf, WtM, bm, (float*)d_out);
}